// Round 15
// baseline (163.689 us; speedup 1.0000x reference)
//
#include <hip/hip_runtime.h>
#include <hip/hip_bf16.h>

#define LDIM 8192
#define HDIM 16
#define DDIM 64
#define NHEADPAIR 64          // N*H
#define ROWSTRIDE 1024        // H*D floats between consecutive l for fixed h
#define KVSZ 4160             // 64*64 KV + 64 ksum
#define EPSF 1e-6f
#define CHUNKS 128            // l-chunks per (n,h)
#define RPB 64                // rows per block = LDIM/CHUNKS
#define LROW 36               // padded LDS row in uints (32 s-pair slots + 4 pad)

typedef float f32x4 __attribute__((ext_vector_type(4)));
typedef short s16x8 __attribute__((ext_vector_type(8)));   // 8 bf16 (4 VGPRs)

__device__ __forceinline__ float featmap(float x) {
    // elu(x)+1 : x>0 -> x+1 ; x<=0 -> exp(x)
    return x > 0.0f ? x + 1.0f : __expf(x);
}

__device__ __forceinline__ unsigned int pack_bf16x2(float a, float b) {
    union { __hip_bfloat162 h; unsigned int u; } x;
    x.h = __float22bfloat162_rn(make_float2(a, b));   // elem0 -> low 16 bits
    return x.u;
}

__device__ __forceinline__ unsigned short bf16_of(float a) {
    union { __hip_bfloat16 h; unsigned short u; } cv;
    cv.h = __float2bfloat16(a);
    return cv.u;
}

// validated swizzle: XOR s-pair slot bits 2-3 with d bits 3-4 (16B-align-preserving)
__device__ __forceinline__ int swz(int d) { return ((d >> 3) & 3) << 2; }

// ---------------- Phase 1 (one-shot MFMA, small tile): partial KV[d][m], Ksum[d] ----
// R14 structure, tile halved (64 rows): LDS 18.4KB -> 8 blocks/CU (was 4). VGPR=52
// already permits 8 waves/SIMD; LDS was the sole occupancy cap. Doubling resident
// staging waves doubles outstanding bytes/CU (the Little's-law limiter: need ~22KB,
// had ~12KB). Partials emitted bf16 to keep the ws footprint at the proven 68MB.
__global__ __launch_bounds__(256) void kv_oneshot_kernel(
    const float* __restrict__ Kp, const float* __restrict__ Vp,
    unsigned short* __restrict__ part)
{
    __shared__ unsigned int KT[64 * LROW];   // [d][s-pair ^ swz(d)]
    __shared__ unsigned int VT[64 * LROW];   // [m][s-pair ^ swz(m)]

    const int ch   = blockIdx.x;             // l-chunk
    const int nh   = blockIdx.y;
    const int n    = nh >> 4;
    const int h    = nh & 15;
    const int t    = threadIdx.x;
    const int wave = t >> 6;
    const int lane = t & 63;

    // staging map: t<128 stage K (+featmap), t>=128 stage V.
    // thread u: col-group dg (floats dg*8..+7), s-pairs rp, rp+16.
    const bool isK = (t < 128);
    const int  u   = t & 127;
    const int  dg  = u & 7;
    const int  rp  = u >> 3;                 // 0..15
    const float* Sp = isK ? Kp : Vp;
    const size_t base = (((size_t)n * LDIM + (size_t)ch * RPB) * HDIM + h) * DDIM
                      + dg * 8;

    // ---- issue the 8 global float4 loads ----
    float4 st[2][4];
#pragma unroll
    for (int i = 0; i < 2; ++i) {
        const int sp = rp + 16 * i;
        const float* g = Sp + base + (size_t)(2 * sp) * ROWSTRIDE;
        st[i][0] = *(const float4*)(g);
        st[i][1] = *(const float4*)(g + 4);
        st[i][2] = *(const float4*)(g + ROWSTRIDE);
        st[i][3] = *(const float4*)(g + ROWSTRIDE + 4);
    }

    // ---- transform + LDS write ----
    unsigned int* T = isK ? KT : VT;
#pragma unroll
    for (int i = 0; i < 2; ++i) {
        const int sp = rp + 16 * i;
        const float* a = (const float*)&st[i][0];   // even row, 8 floats
        const float* b = (const float*)&st[i][2];   // odd row, 8 floats
#pragma unroll
        for (int j = 0; j < 8; ++j) {
            const int d = dg * 8 + j;
            float fe = a[j], fo = b[j];
            if (isK) { fe = featmap(fe); fo = featmap(fo); }
            T[d * LROW + (sp ^ swz(d))] = pack_bf16x2(fe, fo);
        }
    }
    __syncthreads();

    // ---- compute: wave = 16-d band; 2 k-steps x (1 ksum + 4 m-tile) MFMAs ----
    const int fr = lane & 15;
    const int fk = lane >> 4;
    const int d0 = wave * 16;

    f32x4 acc[4];
    f32x4 zac = (f32x4){0.f, 0.f, 0.f, 0.f};
#pragma unroll
    for (int mb = 0; mb < 4; ++mb) acc[mb] = (f32x4){0.f, 0.f, 0.f, 0.f};
    s16x8 ones;
#pragma unroll
    for (int i = 0; i < 8; ++i) ones[i] = (short)0x3F80;   // bf16 1.0

    const int dA = d0 + fr;
#pragma unroll
    for (int kk = 0; kk < 2; ++kk) {
        const int slot = kk * 16 + fk * 4;
        s16x8 A = *(const s16x8*)&KT[dA * LROW + (slot ^ swz(dA))];
        zac = __builtin_amdgcn_mfma_f32_16x16x32_bf16(A, ones, zac, 0, 0, 0);
#pragma unroll
        for (int mb = 0; mb < 4; ++mb) {
            const int m = mb * 16 + fr;
            s16x8 B = *(const s16x8*)&VT[m * LROW + (slot ^ swz(m))];
            acc[mb] = __builtin_amdgcn_mfma_f32_16x16x32_bf16(A, B, acc[mb], 0, 0, 0);
        }
    }

    // ---- epilogue: bf16 partial. D row = d (fk*4+reg), D col = m (fr) ----
    unsigned short* p = part + ((size_t)nh * CHUNKS + ch) * KVSZ;
#pragma unroll
    for (int mb = 0; mb < 4; ++mb)
#pragma unroll
        for (int reg = 0; reg < 4; ++reg)
            p[(d0 + fk * 4 + reg) * 64 + mb * 16 + fr] = bf16_of(acc[mb][reg]);
    if (fr == 0)
#pragma unroll
        for (int reg = 0; reg < 4; ++reg)
            p[4096 + d0 + fk * 4 + reg] = bf16_of(zac[reg]);
}

// ---------------- Phase 1b: reduce bf16 partials, emit bf16 KV + ksum ---------------
__global__ __launch_bounds__(256) void kv_reduce_kernel(
    const unsigned short* __restrict__ part, unsigned short* __restrict__ kvh)
{
    const int nh = blockIdx.y;
    const int e  = blockIdx.x * 256 + threadIdx.x;
    if (e >= KVSZ) return;
    float s = 0.0f;
    for (int c = 0; c < CHUNKS; ++c) {
        union { unsigned short u; __hip_bfloat16 h; } cv;
        cv.u = part[((size_t)nh * CHUNKS + c) * KVSZ + e];
        s += __bfloat162float(cv.h);
    }
    kvh[(size_t)nh * KVSZ + e] = bf16_of(s);
}

// ---------------- Phase 2 (MFMA): out[l][m] = Z * sum_d fmQ[l][d] * KV[m][d] --------
// Unchanged (validated).
__global__ __launch_bounds__(256) void attn_mfma_kernel(
    const float* __restrict__ Qp, const unsigned short* __restrict__ kvh,
    float* __restrict__ out)
{
    __shared__ unsigned int kvU[64][36];
    __shared__ unsigned int ksU[36];
    __shared__ unsigned int qU[128][36];

    const int nh = blockIdx.y;
    const int n  = nh >> 4;
    const int h  = nh & 15;
    const int t  = threadIdx.x;

    {
        const unsigned int* kvg = (const unsigned int*)(kvh + (size_t)nh * KVSZ);
        const int r  = t >> 2;
        const int c0 = (t & 3) * 8;
        uint4 x = *(const uint4*)(kvg + r * 32 + c0);
        uint4 y = *(const uint4*)(kvg + r * 32 + c0 + 4);
        *(uint4*)&kvU[r][c0]     = x;
        *(uint4*)&kvU[r][c0 + 4] = y;
        if (t < 32) ksU[t] = kvg[2048 + t];
    }

    {
        const int qr = t >> 1;
        const float* qg = Qp + ((((size_t)n * LDIM) + (size_t)blockIdx.x * 128 + qr)
                                * HDIM + h) * DDIM + (t & 1) * 32;
        unsigned int q[16];
#pragma unroll
        for (int j = 0; j < 8; ++j) {
            float4 f = *(const float4*)(qg + j * 4);
            q[2 * j]     = pack_bf16x2(featmap(f.x), featmap(f.y));
            q[2 * j + 1] = pack_bf16x2(featmap(f.z), featmap(f.w));
        }
        uint4* dst = (uint4*)&qU[qr][(t & 1) * 16];
        dst[0] = make_uint4(q[0],  q[1],  q[2],  q[3]);
        dst[1] = make_uint4(q[4],  q[5],  q[6],  q[7]);
        dst[2] = make_uint4(q[8],  q[9],  q[10], q[11]);
        dst[3] = make_uint4(q[12], q[13], q[14], q[15]);
    }
    __syncthreads();

    const int wave = t >> 6;
    const int lane = t & 63;
    const int fr = lane & 15;
    const int fk = lane >> 4;

    s16x8 bF[4][2], kF[2];
#pragma unroll
    for (int mt = 0; mt < 4; ++mt)
#pragma unroll
        for (int kk = 0; kk < 2; ++kk)
            bF[mt][kk] = *(const s16x8*)&kvU[mt * 16 + fr][kk * 16 + fk * 4];
#pragma unroll
    for (int kk = 0; kk < 2; ++kk)
        kF[kk] = *(const s16x8*)&ksU[kk * 16 + fk * 4];

    f32x4 acc[2][4];
    f32x4 zac[2];
#pragma unroll
    for (int lt = 0; lt < 2; ++lt) {
        zac[lt] = (f32x4){0.f, 0.f, 0.f, 0.f};
#pragma unroll
        for (int mt = 0; mt < 4; ++mt) acc[lt][mt] = (f32x4){0.f, 0.f, 0.f, 0.f};
    }

#pragma unroll
    for (int kk = 0; kk < 2; ++kk) {
#pragma unroll
        for (int lt = 0; lt < 2; ++lt) {
            s16x8 A = *(const s16x8*)&qU[wave * 32 + lt * 16 + fr][kk * 16 + fk * 4];
            zac[lt] = __builtin_amdgcn_mfma_f32_16x16x32_bf16(A, kF[kk], zac[lt], 0, 0, 0);
#pragma unroll
            for (int mt = 0; mt < 4; ++mt)
                acc[lt][mt] = __builtin_amdgcn_mfma_f32_16x16x32_bf16(
                    A, bF[mt][kk], acc[lt][mt], 0, 0, 0);
        }
    }

#pragma unroll
    for (int lt = 0; lt < 2; ++lt) {
#pragma unroll
        for (int reg = 0; reg < 4; ++reg) {
            const int row = blockIdx.x * 128 + wave * 32 + lt * 16 + fk * 4 + reg;
            const float z = 1.0f / (zac[lt][reg] + EPSF);
            float* orow = out + (((size_t)n * LDIM + row) * HDIM + h) * DDIM;
#pragma unroll
            for (int mt = 0; mt < 4; ++mt)
                orow[mt * 16 + fr] = acc[lt][mt][reg] * z;
        }
    }
}

extern "C" void kernel_launch(void* const* d_in, const int* in_sizes, int n_in,
                              void* d_out, int out_size, void* d_ws, size_t ws_size,
                              hipStream_t stream) {
    const float* Q = (const float*)d_in[0];
    const float* K = (const float*)d_in[1];
    const float* V = (const float*)d_in[2];
    float* out = (float*)d_out;

    unsigned short* part = (unsigned short*)d_ws;   // 64*128*4160*2 = 68.2 MB
    unsigned short* kvh  = part + (size_t)NHEADPAIR * CHUNKS * KVSZ;

    dim3 g1(CHUNKS, NHEADPAIR);              // 8192 one-shot blocks, 8/CU resident
    kv_oneshot_kernel<<<g1, 256, 0, stream>>>(K, V, part);
    dim3 gr((KVSZ + 255) / 256, NHEADPAIR);
    kv_reduce_kernel<<<gr, 256, 0, stream>>>(part, kvh);
    dim3 g2(LDIM / 128, NHEADPAIR);
    attn_mfma_kernel<<<g2, 256, 0, stream>>>(Q, kvh, out);
}

// Round 16
// 157.955 us; speedup vs baseline: 1.0363x; 1.0363x over previous
//
#include <hip/hip_runtime.h>
#include <hip/hip_bf16.h>

#define LDIM 8192
#define HDIM 16
#define DDIM 64
#define NHEADPAIR 64          // N*H
#define ROWSTRIDE 1024        // H*D floats between consecutive l for fixed h
#define KVSZ 4160             // 64*64 KV + 64 ksum
#define EPSF 1e-6f
#define CHUNKS 128            // l-chunks per (n,h)
#define RPB 64                // rows per block = LDIM/CHUNKS
#define LROW 36               // padded LDS row in uints (32 l-pair slots + 4 pad)

typedef float f32x4 __attribute__((ext_vector_type(4)));
typedef short s16x8 __attribute__((ext_vector_type(8)));   // 8 bf16 (4 VGPRs)

__device__ __forceinline__ float featmap(float x) {
    // elu(x)+1 : x>0 -> x+1 ; x<=0 -> exp(x)
    return x > 0.0f ? x + 1.0f : __expf(x);
}

__device__ __forceinline__ unsigned int pack_bf16x2(float a, float b) {
    union { __hip_bfloat162 h; unsigned int u; } x;
    x.h = __float22bfloat162_rn(make_float2(a, b));   // elem0 -> low 16 bits
    return x.u;
}

__device__ __forceinline__ unsigned short bf16_of(float a) {
    union { __hip_bfloat16 h; unsigned short u; } cv;
    cv.h = __float2bfloat16(a);
    return cv.u;
}

// validated swizzle: XOR slot bits 2-3 with d bits 3-4 (16B-align-preserving)
__device__ __forceinline__ int swz(int d) { return ((d >> 3) & 3) << 2; }

// ---------------- Phase 1 (one-shot MFMA, dense-instruction staging) ----------------
// Identical to R15 EXCEPT the staging lane map: lanes 0-15 cover ONE row's 256B
// contiguously (col16 = lane&15), rv = lane>>4 picks 4 rows -> each load instruction
// = 4 fully-dense 256B segments (16 fully-used 64B lines) instead of 64 scattered
// half-used 16B requests. Thread pairs rows (r, r+4) into one bf16x2 uint; the k-axis
// permutation this induces is identical for K and V (same map), so the contraction
// is unaffected; ksum uses all-ones B (order-free).
__global__ __launch_bounds__(256) void kv_oneshot_kernel(
    const float* __restrict__ Kp, const float* __restrict__ Vp,
    unsigned short* __restrict__ part)
{
    __shared__ unsigned int KT[64 * LROW];   // [d][slot ^ swz(d)]
    __shared__ unsigned int VT[64 * LROW];   // [m][slot ^ swz(m)]

    const int ch   = blockIdx.x;             // l-chunk
    const int nh   = blockIdx.y;
    const int n    = nh >> 4;
    const int h    = nh & 15;
    const int t    = threadIdx.x;
    const int wave = t >> 6;
    const int lane = t & 63;

    // staging: t<128 (waves 0-1) stage K (+featmap), t>=128 stage V.
    const bool isK   = (t < 128);
    const int  uw    = (t >> 6) & 1;         // sub-wave within the K/V half
    const int  col16 = lane & 15;            // 16B granule within a 256B row
    const int  rv    = lane >> 4;            // row-in-quad 0..3
    const float* Sp  = isK ? Kp : Vp;
    const size_t base = (((size_t)n * LDIM + (size_t)ch * RPB) * HDIM + h) * DDIM
                      + col16 * 4;
    unsigned int* T = isK ? KT : VT;

#pragma unroll
    for (int g = 0; g < 4; ++g) {
        const int gg = uw * 4 + g;           // 8-row group 0..7
        const int r1 = gg * 8 + rv;          // rows rv, rv+4 of the group
        const int r2 = r1 + 4;
        float4 L1 = *(const float4*)(Sp + base + (size_t)r1 * ROWSTRIDE);
        float4 L2 = *(const float4*)(Sp + base + (size_t)r2 * ROWSTRIDE);
        float a[4] = { L1.x, L1.y, L1.z, L1.w };
        float b[4] = { L2.x, L2.y, L2.z, L2.w };
        if (isK) {
#pragma unroll
            for (int j = 0; j < 4; ++j) { a[j] = featmap(a[j]); b[j] = featmap(b[j]); }
        }
        const int slot = gg * 4 + rv;        // 0..31
#pragma unroll
        for (int j = 0; j < 4; ++j) {
            const int d = col16 * 4 + j;
            T[d * LROW + (slot ^ swz(d))] = pack_bf16x2(a[j], b[j]);
        }
    }
    __syncthreads();

    // ---- compute: wave = 16-d band; 2 k-steps x (1 ksum + 4 m-tile) MFMAs ----
    const int fr = lane & 15;
    const int fk = lane >> 4;
    const int d0 = wave * 16;

    f32x4 acc[4];
    f32x4 zac = (f32x4){0.f, 0.f, 0.f, 0.f};
#pragma unroll
    for (int mb = 0; mb < 4; ++mb) acc[mb] = (f32x4){0.f, 0.f, 0.f, 0.f};
    s16x8 ones;
#pragma unroll
    for (int i = 0; i < 8; ++i) ones[i] = (short)0x3F80;   // bf16 1.0

    const int dA = d0 + fr;
#pragma unroll
    for (int kk = 0; kk < 2; ++kk) {
        const int slot = kk * 16 + fk * 4;
        s16x8 A = *(const s16x8*)&KT[dA * LROW + (slot ^ swz(dA))];
        zac = __builtin_amdgcn_mfma_f32_16x16x32_bf16(A, ones, zac, 0, 0, 0);
#pragma unroll
        for (int mb = 0; mb < 4; ++mb) {
            const int m = mb * 16 + fr;
            s16x8 B = *(const s16x8*)&VT[m * LROW + (slot ^ swz(m))];
            acc[mb] = __builtin_amdgcn_mfma_f32_16x16x32_bf16(A, B, acc[mb], 0, 0, 0);
        }
    }

    // ---- epilogue: bf16 partial. D row = d (fk*4+reg), D col = m (fr) ----
    unsigned short* p = part + ((size_t)nh * CHUNKS + ch) * KVSZ;
#pragma unroll
    for (int mb = 0; mb < 4; ++mb)
#pragma unroll
        for (int reg = 0; reg < 4; ++reg)
            p[(d0 + fk * 4 + reg) * 64 + mb * 16 + fr] = bf16_of(acc[mb][reg]);
    if (fr == 0)
#pragma unroll
        for (int reg = 0; reg < 4; ++reg)
            p[4096 + d0 + fk * 4 + reg] = bf16_of(zac[reg]);
}

// ---------------- Phase 1b: reduce bf16 partials, emit bf16 KV + ksum ---------------
__global__ __launch_bounds__(256) void kv_reduce_kernel(
    const unsigned short* __restrict__ part, unsigned short* __restrict__ kvh)
{
    const int nh = blockIdx.y;
    const int e  = blockIdx.x * 256 + threadIdx.x;
    if (e >= KVSZ) return;
    float s = 0.0f;
    for (int c = 0; c < CHUNKS; ++c) {
        union { unsigned short u; __hip_bfloat16 h; } cv;
        cv.u = part[((size_t)nh * CHUNKS + c) * KVSZ + e];
        s += __bfloat162float(cv.h);
    }
    kvh[(size_t)nh * KVSZ + e] = bf16_of(s);
}

// ---------------- Phase 2 (MFMA): out[l][m] = Z * sum_d fmQ[l][d] * KV[m][d] --------
// Unchanged (validated).
__global__ __launch_bounds__(256) void attn_mfma_kernel(
    const float* __restrict__ Qp, const unsigned short* __restrict__ kvh,
    float* __restrict__ out)
{
    __shared__ unsigned int kvU[64][36];
    __shared__ unsigned int ksU[36];
    __shared__ unsigned int qU[128][36];

    const int nh = blockIdx.y;
    const int n  = nh >> 4;
    const int h  = nh & 15;
    const int t  = threadIdx.x;

    {
        const unsigned int* kvg = (const unsigned int*)(kvh + (size_t)nh * KVSZ);
        const int r  = t >> 2;
        const int c0 = (t & 3) * 8;
        uint4 x = *(const uint4*)(kvg + r * 32 + c0);
        uint4 y = *(const uint4*)(kvg + r * 32 + c0 + 4);
        *(uint4*)&kvU[r][c0]     = x;
        *(uint4*)&kvU[r][c0 + 4] = y;
        if (t < 32) ksU[t] = kvg[2048 + t];
    }

    {
        const int qr = t >> 1;
        const float* qg = Qp + ((((size_t)n * LDIM) + (size_t)blockIdx.x * 128 + qr)
                                * HDIM + h) * DDIM + (t & 1) * 32;
        unsigned int q[16];
#pragma unroll
        for (int j = 0; j < 8; ++j) {
            float4 f = *(const float4*)(qg + j * 4);
            q[2 * j]     = pack_bf16x2(featmap(f.x), featmap(f.y));
            q[2 * j + 1] = pack_bf16x2(featmap(f.z), featmap(f.w));
        }
        uint4* dst = (uint4*)&qU[qr][(t & 1) * 16];
        dst[0] = make_uint4(q[0],  q[1],  q[2],  q[3]);
        dst[1] = make_uint4(q[4],  q[5],  q[6],  q[7]);
        dst[2] = make_uint4(q[8],  q[9],  q[10], q[11]);
        dst[3] = make_uint4(q[12], q[13], q[14], q[15]);
    }
    __syncthreads();

    const int wave = t >> 6;
    const int lane = t & 63;
    const int fr = lane & 15;
    const int fk = lane >> 4;

    s16x8 bF[4][2], kF[2];
#pragma unroll
    for (int mt = 0; mt < 4; ++mt)
#pragma unroll
        for (int kk = 0; kk < 2; ++kk)
            bF[mt][kk] = *(const s16x8*)&kvU[mt * 16 + fr][kk * 16 + fk * 4];
#pragma unroll
    for (int kk = 0; kk < 2; ++kk)
        kF[kk] = *(const s16x8*)&ksU[kk * 16 + fk * 4];

    f32x4 acc[2][4];
    f32x4 zac[2];
#pragma unroll
    for (int lt = 0; lt < 2; ++lt) {
        zac[lt] = (f32x4){0.f, 0.f, 0.f, 0.f};
#pragma unroll
        for (int mt = 0; mt < 4; ++mt) acc[lt][mt] = (f32x4){0.f, 0.f, 0.f, 0.f};
    }

#pragma unroll
    for (int kk = 0; kk < 2; ++kk) {
#pragma unroll
        for (int lt = 0; lt < 2; ++lt) {
            s16x8 A = *(const s16x8*)&qU[wave * 32 + lt * 16 + fr][kk * 16 + fk * 4];
            zac[lt] = __builtin_amdgcn_mfma_f32_16x16x32_bf16(A, kF[kk], zac[lt], 0, 0, 0);
#pragma unroll
            for (int mt = 0; mt < 4; ++mt)
                acc[lt][mt] = __builtin_amdgcn_mfma_f32_16x16x32_bf16(
                    A, bF[mt][kk], acc[lt][mt], 0, 0, 0);
        }
    }

#pragma unroll
    for (int lt = 0; lt < 2; ++lt) {
#pragma unroll
        for (int reg = 0; reg < 4; ++reg) {
            const int row = blockIdx.x * 128 + wave * 32 + lt * 16 + fk * 4 + reg;
            const float z = 1.0f / (zac[lt][reg] + EPSF);
            float* orow = out + (((size_t)n * LDIM + row) * HDIM + h) * DDIM;
#pragma unroll
            for (int mt = 0; mt < 4; ++mt)
                orow[mt * 16 + fr] = acc[lt][mt][reg] * z;
        }
    }
}

extern "C" void kernel_launch(void* const* d_in, const int* in_sizes, int n_in,
                              void* d_out, int out_size, void* d_ws, size_t ws_size,
                              hipStream_t stream) {
    const float* Q = (const float*)d_in[0];
    const float* K = (const float*)d_in[1];
    const float* V = (const float*)d_in[2];
    float* out = (float*)d_out;

    unsigned short* part = (unsigned short*)d_ws;   // 64*128*4160*2 = 68.2 MB
    unsigned short* kvh  = part + (size_t)NHEADPAIR * CHUNKS * KVSZ;

    dim3 g1(CHUNKS, NHEADPAIR);              // 8192 one-shot blocks, 8/CU resident
    kv_oneshot_kernel<<<g1, 256, 0, stream>>>(K, V, part);
    dim3 gr((KVSZ + 255) / 256, NHEADPAIR);
    kv_reduce_kernel<<<gr, 256, 0, stream>>>(part, kvh);
    dim3 g2(LDIM / 128, NHEADPAIR);
    attn_mfma_kernel<<<g2, 256, 0, stream>>>(Q, kvh, out);
}